// Round 13
// baseline (85.690 us; speedup 1.0000x reference)
//
#include <hip/hip_runtime.h>
#include <hip/hip_bf16.h>

#define FEPS 1e-5f

constexpr int Bn = 4, Hn = 16, Sn = 4096, Dn = 64;
constexpr int NHEAD = Bn * Hn;          // 64 heads
constexpr int SLOT = Dn * Dn + Dn;      // final fp32 slot: 4096 kv + 64 ksum
constexpr int SLOTW = Dn * Dn / 2 + Dn; // per-WAVE partial: 2048 u32 bf16-kv + 64 f32 ksum

typedef short short8 __attribute__((ext_vector_type(8)));
typedef float f32x4 __attribute__((ext_vector_type(4)));

__device__ __forceinline__ unsigned short f2bfu(float f) {
    __hip_bfloat16 h = __float2bfloat16(f);
    return __builtin_bit_cast(unsigned short, h);
}
__device__ __forceinline__ unsigned pack2(float a, float b) {
    return (unsigned)f2bfu(a) | ((unsigned)f2bfu(b) << 16);
}
__device__ __forceinline__ float elem4(const float4& v, int i) {
    return i == 0 ? v.x : i == 1 ? v.y : i == 2 ? v.z : v.w;
}

// ---------------- Pass 1 (MFMA): ZERO LDS, ZERO barriers, per-wave slot ----------------
// Every prior variant (R1..R12, 5 structures, all 53-65us) shared a multi-
// barrier serialized LDS epilogue; this kernel removes ALL intra-block
// coupling. Each wave: 32 coalesced dwordx4 loads (2 slices in flight) ->
// CVT -> 32 MFMA -> 16 coalesced dwordx2 bf16 stores to its OWN slot.
// Column-permuted fragments (proven R10): tile mt owns d-cols {4c+mt}; A/B
// share the (lane,j)->s map so k-pairing is layout-invariant.
// Store layout: lane(q16,lc) holds d=16q16+4r+mt, e=4lc+nt; uint2 of
// {pack2(nt0,nt1), pack2(nt2,nt3)} at word d*32+2lc -> 16 lanes x 8B = 128B
// contiguous segments. launch_bounds(256,1): allow ~200 VGPR so the load
// pipeline stays in registers (R11: (256,2) made compiler sink loads).
__global__ __launch_bounds__(256, 1) void pass1(const float* __restrict__ K,
                                                const float* __restrict__ V,
                                                unsigned* __restrict__ partw,
                                                int ch_s) {
    const int head = blockIdx.x;
    const int chunk = blockIdx.y;
    const int t = threadIdx.x;
    const int w = t >> 6;                  // wave 0..3
    const int l = t & 63;
    const int q16 = l >> 4;                // lane group 0..3
    const int lc = l & 15;                 // lane col 0..15
    const int wave_s = ch_s >> 2;          // s-rows per wave
    const int nsl = wave_s >> 5;           // 32-row slices per wave (even)

    const size_t hbase = (size_t)head * Sn * Dn;
    const size_t s0w = (size_t)chunk * ch_s + (size_t)w * wave_s;
    const float4* Kp4 = (const float4*)(K + hbase + (s0w + q16 * 8) * Dn) + lc;
    const float4* Vp4 = (const float4*)(V + hbase + (s0w + q16 * 8) * Dn) + lc;

    f32x4 acc[4][4] = {};                  // [mt][nt]; d=4*m_loc+mt, e=4*n_loc+nt
    float ks[4] = {0.f, 0.f, 0.f, 0.f};    // fp32 ksum partial for col 4*lc+mt

    float4 krA[8], vrA[8], krB[8], vrB[8];
    short8 af[4], bfr[4];

    auto LOAD = [&](int sl, float4* kr, float4* vr) {
        #pragma unroll
        for (int j = 0; j < 8; ++j) {
            kr[j] = Kp4[(sl * 32 + j) * 16];
            vr[j] = Vp4[(sl * 32 + j) * 16];
        }
    };
    auto CVT = [&](const float4* kr, const float4* vr) {
        #pragma unroll
        for (int mt = 0; mt < 4; ++mt) {
            short8 a, b;
            #pragma unroll
            for (int j = 0; j < 8; ++j) {
                float kf = elem4(kr[j], mt);
                float vf = elem4(vr[j], mt);
                a[j] = (short)f2bfu(kf);
                ks[mt] += kf;
                b[j] = (short)f2bfu(vf);
            }
            af[mt] = a;
            bfr[mt] = b;
        }
    };
    auto MM = [&]() {
        #pragma unroll
        for (int mt = 0; mt < 4; ++mt)
            #pragma unroll
            for (int nt = 0; nt < 4; ++nt)
                acc[mt][nt] = __builtin_amdgcn_mfma_f32_16x16x32_bf16(
                    af[mt], bfr[nt], acc[mt][nt], 0, 0, 0);
    };

    if (nsl == 2) {                        // chunks=16 fast path: all 32 loads in flight
        LOAD(0, krA, vrA);
        LOAD(1, krB, vrB);
        CVT(krA, vrA); MM();
        CVT(krB, vrB); MM();
    } else {                               // generic even-nsl A/B pipeline
        LOAD(0, krA, vrA);
        for (int sl = 0; sl < nsl; sl += 2) {
            if (sl + 1 < nsl) LOAD(sl + 1, krB, vrB);
            CVT(krA, vrA); MM();
            if (sl + 1 >= nsl) break;
            if (sl + 2 < nsl) LOAD(sl + 2, krA, vrA);
            CVT(krB, vrB); MM();
        }
    }

    // ksum: reduce across the 4 q16 lane groups (wave-local)
    #pragma unroll
    for (int mt = 0; mt < 4; ++mt) {
        ks[mt] += __shfl_xor(ks[mt], 16);
        ks[mt] += __shfl_xor(ks[mt], 32);
    }

    // per-wave slot write: kv bf16-packed, coalesced uint2
    unsigned* slot = partw + (((size_t)chunk * NHEAD + head) * 4 + w) * SLOTW;
    #pragma unroll
    for (int mt = 0; mt < 4; ++mt)
        #pragma unroll
        for (int r = 0; r < 4; ++r) {
            int d = 16 * q16 + 4 * r + mt;
            uint2 p;
            p.x = pack2(acc[mt][0][r], acc[mt][1][r]);   // e = 4lc+0, 4lc+1
            p.y = pack2(acc[mt][2][r], acc[mt][3][r]);   // e = 4lc+2, 4lc+3
            *(uint2*)&slot[d * 32 + 2 * lc] = p;
        }
    if (l < 16) {
        #pragma unroll
        for (int mt = 0; mt < 4; ++mt)
            slot[Dn * Dn / 2 + 4 * l + mt] =
                __builtin_bit_cast(unsigned, ks[mt]);
    }
}

// ---------------- Reduce per-wave bf16 partials -> final fp32 slots ----------------
__global__ __launch_bounds__(256) void reduce_partials(const unsigned* __restrict__ partw,
                                                       float* __restrict__ slots,
                                                       int nslots) {   // chunks*4 per head
    const int head = blockIdx.x;
    const int idx = blockIdx.y * 256 + threadIdx.x;
    if (idx >= SLOTW) return;
    const int chunks = nslots >> 2;
    if (idx < Dn * Dn / 2) {
        float lo = 0.f, hi = 0.f;
        for (int c = 0; c < chunks; ++c) {
            const unsigned* base =
                partw + (((size_t)c * NHEAD + head) * 4) * SLOTW + idx;
            #pragma unroll
            for (int ww = 0; ww < 4; ++ww) {
                unsigned u = base[(size_t)ww * SLOTW];
                lo += __builtin_bit_cast(float, u << 16);
                hi += __builtin_bit_cast(float, u & 0xffff0000u);
            }
        }
        // word idx: d = idx>>5, epair = idx&31 -> e = 2*epair
        int kvi = (idx >> 5) * Dn + (idx & 31) * 2;
        float* dst = slots + (size_t)head * SLOT + kvi;
        dst[0] = lo;
        dst[1] = hi;
    } else {
        float s = 0.f;
        for (int c = 0; c < chunks; ++c) {
            const unsigned* base =
                partw + (((size_t)c * NHEAD + head) * 4) * SLOTW + idx;
            #pragma unroll
            for (int ww = 0; ww < 4; ++ww)
                s += __builtin_bit_cast(float, base[(size_t)ww * SLOTW]);
        }
        slots[(size_t)head * SLOT + Dn * Dn + (idx - Dn * Dn / 2)] = s;
    }
}

// ---------------- Pass 2: out = (Q / (Q.ksum + eps)) @ kv ----------------
__global__ __launch_bounds__(256) void pass2(const float* __restrict__ Q,
                                             const float* __restrict__ slots,
                                             float* __restrict__ out) {
    const int head = blockIdx.x;
    const int rc = blockIdx.y;  // 64-row chunk
    const int t = threadIdx.x;
    const int ti = t >> 4, tj = t & 15;
    const int r0 = ti * 4, e0 = tj * 4;   // 4 rows x 4 cols per thread

    __shared__ float kvs[Dn][Dn];
    __shared__ float qT[Dn][68];          // transposed Q tile, padded
    __shared__ float kss[Dn];

    const float* kvh = slots + (size_t)head * SLOT;

    const float4* kvsrc = (const float4*)kvh;
    float4* kvdst = (float4*)&kvs[0][0];
    #pragma unroll
    for (int kk = 0; kk < 4; ++kk) kvdst[t + 256 * kk] = kvsrc[t + 256 * kk];
    if (t < 16) ((float4*)kss)[t] = ((const float4*)(kvh + Dn * Dn))[t];

    const float4* Qsrc = (const float4*)(Q + ((size_t)head * Sn + (size_t)rc * 64) * Dn);
    #pragma unroll
    for (int kk = 0; kk < 4; ++kk) {
        int f = t + 256 * kk;
        int row = f >> 4, d4 = (f & 15) * 4;
        float4 q4 = Qsrc[f];
        qT[d4 + 0][row] = q4.x;
        qT[d4 + 1][row] = q4.y;
        qT[d4 + 2][row] = q4.z;
        qT[d4 + 3][row] = q4.w;
    }
    __syncthreads();

    float acc[4][4] = {};
    float dn[4] = {0.f, 0.f, 0.f, 0.f};
    #pragma unroll 8
    for (int d = 0; d < Dn; ++d) {
        float4 a = *(const float4*)&qT[d][r0];
        float4 b = *(const float4*)&kvs[d][e0];
        float ksd = kss[d];
        float av[4] = {a.x, a.y, a.z, a.w};
        float bv[4] = {b.x, b.y, b.z, b.w};
        #pragma unroll
        for (int i = 0; i < 4; ++i) {
            dn[i] += av[i] * ksd;
            #pragma unroll
            for (int j = 0; j < 4; ++j) acc[i][j] += av[i] * bv[j];
        }
    }

    float* Oh = out + ((size_t)head * Sn + (size_t)rc * 64) * Dn;
    #pragma unroll
    for (int i = 0; i < 4; ++i) {
        float inv = 1.0f / (dn[i] + FEPS);
        float4 r;
        r.x = acc[i][0] * inv; r.y = acc[i][1] * inv;
        r.z = acc[i][2] * inv; r.w = acc[i][3] * inv;
        *(float4*)&Oh[(size_t)(r0 + i) * Dn + e0] = r;
    }
}

extern "C" void kernel_launch(void* const* d_in, const int* in_sizes, int n_in,
                              void* d_out, int out_size, void* d_ws, size_t ws_size,
                              hipStream_t stream) {
    (void)in_sizes; (void)n_in; (void)out_size;
    const float* Q = (const float*)d_in[0];
    const float* K = (const float*)d_in[1];
    const float* V = (const float*)d_in[2];
    float* out = (float*)d_out;

    float* slots = (float*)d_ws;                                 // [64][4160] fp32
    unsigned* partw = (unsigned*)(slots + (size_t)NHEAD * SLOT); // [chunks][64][4][2112]

    // largest chunk count whose per-wave partial buffer fits (16 preferred: nsl=2)
    int chunks = 2;
    const int cand[4] = {16, 8, 4, 2};
    for (int ci = 0; ci < 4; ++ci) {
        size_t need = (size_t)NHEAD * SLOT * 4 +
                      (size_t)cand[ci] * NHEAD * 4 * SLOTW * 4;
        if (need <= ws_size) { chunks = cand[ci]; break; }
    }

    hipLaunchKernelGGL(pass1, dim3(NHEAD, chunks), dim3(256), 0, stream,
                       K, V, partw, Sn / chunks);
    hipLaunchKernelGGL(reduce_partials, dim3(NHEAD, (SLOTW + 255) / 256), dim3(256), 0, stream,
                       partw, slots, chunks * 4);
    hipLaunchKernelGGL(pass2, dim3(NHEAD, Sn / 64), dim3(256), 0, stream,
                       Q, slots, out);
}

// Round 15
// 78.105 us; speedup vs baseline: 1.0971x; 1.0971x over previous
//
#include <hip/hip_runtime.h>
#include <hip/hip_bf16.h>

#define FEPS 1e-5f

constexpr int Bn = 4, Hn = 16, Sn = 4096, Dn = 64;
constexpr int NHEAD = Bn * Hn;          // 64 heads
constexpr int SLOT = Dn * Dn + Dn;      // 4160 floats: kv then ksum

typedef short short8 __attribute__((ext_vector_type(8)));
typedef float f32x4 __attribute__((ext_vector_type(4)));

__device__ __forceinline__ short f2bf(float f) {
    __hip_bfloat16 h = __float2bfloat16(f);
    return __builtin_bit_cast(short, h);
}

// ---------------- Pass 1 (MFMA): partial kv = K^T V and k_sum over an S-chunk ----------------
// R9 configuration verbatim (best measured total: 77.4us; pass1 55.5us).
// Session conclusion: 5 structurally different pass1 schedules (fp32 VALU,
// LDS-staged, barrier-free, coalesced, pipelined) all converge to a sustained
// READ rate of 2.0-2.6 TB/s == 75-85% of the read half of the m13 copy
// ceiling (6.29 TB/s r+w). Occupancy proven irrelevant (R12 25% vs R13 9%,
// same 53us). pass1 is read-path-bound, not schedule-bound.
__global__ __launch_bounds__(256, 2) void pass1(const float* __restrict__ K,
                                                const float* __restrict__ V,
                                                float* __restrict__ part,
                                                int ch_s) {
    __shared__ float red[2048];   // 64 x 32 e-half reduction buffer
    __shared__ float ksr[256];    // per-wave ksum partials

    const int head = blockIdx.x;
    const int chunk = blockIdx.y;
    const int t = threadIdx.x;
    const int w = t >> 6;                  // wave 0..3
    const int l = t & 63;
    const int q16 = l >> 4;                // lane group 0..3
    const int lc = l & 15;                 // col within 16-tile
    const int wave_s = ch_s >> 2;          // s-rows per wave
    const int nsl = wave_s >> 5;           // 32-row slices per wave

    const size_t hbase = (size_t)head * Sn * Dn;
    const size_t s0w = (size_t)chunk * ch_s + (size_t)w * wave_s;
    const float* Kp = K + hbase + (s0w + q16 * 8) * Dn + lc;
    const float* Vp = V + hbase + (s0w + q16 * 8) * Dn + lc;

    f32x4 acc[4][4] = {};                  // [mt(d-tile)][nt(e-tile)]
    float ks[4] = {0.f, 0.f, 0.f, 0.f};    // fp32 ksum partial, d = mt*16+lc

    for (int sl = 0; sl < nsl; ++sl) {
        const float* kp = Kp + (size_t)sl * 32 * Dn;
        const float* vp = Vp + (size_t)sl * 32 * Dn;
        short8 af[4], bf[4];
        #pragma unroll
        for (int mt = 0; mt < 4; ++mt) {
            float f[8];
            #pragma unroll
            for (int j = 0; j < 8; ++j) f[j] = kp[j * Dn + mt * 16];
            short8 a;
            #pragma unroll
            for (int j = 0; j < 8; ++j) { a[j] = f2bf(f[j]); ks[mt] += f[j]; }
            af[mt] = a;
        }
        #pragma unroll
        for (int nt = 0; nt < 4; ++nt) {
            float f[8];
            #pragma unroll
            for (int j = 0; j < 8; ++j) f[j] = vp[j * Dn + nt * 16];
            short8 b;
            #pragma unroll
            for (int j = 0; j < 8; ++j) b[j] = f2bf(f[j]);
            bf[nt] = b;
        }
        #pragma unroll
        for (int mt = 0; mt < 4; ++mt)
            #pragma unroll
            for (int nt = 0; nt < 4; ++nt)
                acc[mt][nt] = __builtin_amdgcn_mfma_f32_16x16x32_bf16(
                    af[mt], bf[nt], acc[mt][nt], 0, 0, 0);
    }

    // ksum: lane covers only its q16-group's s-rows -> reduce across groups
    #pragma unroll
    for (int mt = 0; mt < 4; ++mt) {
        ks[mt] += __shfl_xor(ks[mt], 16);
        ks[mt] += __shfl_xor(ks[mt], 32);
    }
    if (l < 16) {
        #pragma unroll
        for (int mt = 0; mt < 4; ++mt) ksr[w * Dn + mt * 16 + l] = ks[mt];
    }

    // ---- epilogue: reduce 4 wave partials in two 64x32 e-halves ----
    float* slot = part + ((size_t)chunk * NHEAD + head) * SLOT;
    #pragma unroll
    for (int h = 0; h < 2; ++h) {
        #pragma unroll
        for (int ww = 0; ww < 4; ++ww) {
            __syncthreads();
            if (w == ww) {
                #pragma unroll
                for (int mt = 0; mt < 4; ++mt)
                    #pragma unroll
                    for (int nh = 0; nh < 2; ++nh) {   // nt = h*2 + nh
                        #pragma unroll
                        for (int r = 0; r < 4; ++r) {
                            int row = mt * 16 + q16 * 4 + r;
                            int col = nh * 16 + lc;
                            float v = acc[mt][h * 2 + nh][r];
                            if (ww == 0) red[row * 32 + col] = v;
                            else         red[row * 32 + col] += v;
                        }
                    }
            }
        }
        __syncthreads();
        // write this e-half: red[d][eo] -> slot[d*64 + h*32 + eo]
        #pragma unroll
        for (int q = 0; q < 2; ++q) {
            int f = q * 1024 + t * 4;      // 0..2047
            int d = f >> 5, eo = f & 31;
            *(float4*)&slot[d * Dn + h * 32 + eo] = *(const float4*)&red[f];
        }
    }
    if (t < Dn)
        slot[Dn * Dn + t] = ksr[t] + ksr[Dn + t] + ksr[2 * Dn + t] + ksr[3 * Dn + t];
}

// ---------------- Reduce chunk-partials (float4-vectorized) ----------------
__global__ __launch_bounds__(256) void reduce_partials(const float* __restrict__ part,
                                                       float* __restrict__ slots,
                                                       int nchunks) {
    const int head = blockIdx.x;
    const int idx4 = (blockIdx.y * 256 + threadIdx.x) * 4;
    if (idx4 >= SLOT) return;
    float4 s = make_float4(0.f, 0.f, 0.f, 0.f);
    for (int c = 0; c < nchunks; ++c) {
        float4 v = *(const float4*)&part[((size_t)c * NHEAD + head) * SLOT + idx4];
        s.x += v.x; s.y += v.y; s.z += v.z; s.w += v.w;
    }
    *(float4*)&slots[(size_t)head * SLOT + idx4] = s;
}

// ---------------- Pass 2: out = (Q / (Q.ksum + eps)) @ kv ----------------
// Grid transposed vs R9: blockIdx.x = rc, blockIdx.y = head, so consecutive
// blocks share the same head's 16KB kv (same-XCD L2 hits).
__global__ __launch_bounds__(256) void pass2(const float* __restrict__ Q,
                                             const float* __restrict__ slots,
                                             float* __restrict__ out) {
    const int rc = blockIdx.x;   // 64-row chunk
    const int head = blockIdx.y;
    const int t = threadIdx.x;
    const int ti = t >> 4, tj = t & 15;
    const int r0 = ti * 4, e0 = tj * 4;   // 4 rows x 4 cols per thread

    __shared__ float kvs[Dn][Dn];
    __shared__ float qT[Dn][68];          // transposed Q tile, padded
    __shared__ float kss[Dn];

    const float* kvh = slots + (size_t)head * SLOT;

    const float4* kvsrc = (const float4*)kvh;
    float4* kvdst = (float4*)&kvs[0][0];
    #pragma unroll
    for (int kk = 0; kk < 4; ++kk) kvdst[t + 256 * kk] = kvsrc[t + 256 * kk];
    if (t < 16) ((float4*)kss)[t] = ((const float4*)(kvh + Dn * Dn))[t];

    const float4* Qsrc = (const float4*)(Q + ((size_t)head * Sn + (size_t)rc * 64) * Dn);
    #pragma unroll
    for (int kk = 0; kk < 4; ++kk) {
        int f = t + 256 * kk;
        int row = f >> 4, d4 = (f & 15) * 4;
        float4 q4 = Qsrc[f];
        qT[d4 + 0][row] = q4.x;
        qT[d4 + 1][row] = q4.y;
        qT[d4 + 2][row] = q4.z;
        qT[d4 + 3][row] = q4.w;
    }
    __syncthreads();

    float acc[4][4] = {};
    float dn[4] = {0.f, 0.f, 0.f, 0.f};
    #pragma unroll 8
    for (int d = 0; d < Dn; ++d) {
        float4 a = *(const float4*)&qT[d][r0];
        float4 b = *(const float4*)&kvs[d][e0];
        float ksd = kss[d];
        float av[4] = {a.x, a.y, a.z, a.w};
        float bv[4] = {b.x, b.y, b.z, b.w};
        #pragma unroll
        for (int i = 0; i < 4; ++i) {
            dn[i] += av[i] * ksd;
            #pragma unroll
            for (int j = 0; j < 4; ++j) acc[i][j] += av[i] * bv[j];
        }
    }

    float* Oh = out + ((size_t)head * Sn + (size_t)rc * 64) * Dn;
    #pragma unroll
    for (int i = 0; i < 4; ++i) {
        float inv = 1.0f / (dn[i] + FEPS);
        float4 r;
        r.x = acc[i][0] * inv; r.y = acc[i][1] * inv;
        r.z = acc[i][2] * inv; r.w = acc[i][3] * inv;
        *(float4*)&Oh[(size_t)(r0 + i) * Dn + e0] = r;
    }
}

extern "C" void kernel_launch(void* const* d_in, const int* in_sizes, int n_in,
                              void* d_out, int out_size, void* d_ws, size_t ws_size,
                              hipStream_t stream) {
    (void)in_sizes; (void)n_in; (void)out_size;
    const float* Q = (const float*)d_in[0];
    const float* K = (const float*)d_in[1];
    const float* V = (const float*)d_in[2];
    float* out = (float*)d_out;

    float* slots = (float*)d_ws;                         // [64][4160] final kv+ksum

    int chunks = 1;
    const int cand[4] = {16, 8, 4, 2};
    for (int ci = 0; ci < 4; ++ci) {
        if ((size_t)(1 + cand[ci]) * NHEAD * SLOT * sizeof(float) <= ws_size) {
            chunks = cand[ci];
            break;
        }
    }

    if (chunks > 1) {
        float* part = slots + (size_t)NHEAD * SLOT;      // [chunks][64][4160]
        hipLaunchKernelGGL(pass1, dim3(NHEAD, chunks), dim3(256), 0, stream,
                           K, V, part, Sn / chunks);
        hipLaunchKernelGGL(reduce_partials, dim3(NHEAD, (SLOT / 4 + 255) / 256), dim3(256), 0, stream,
                           part, slots, chunks);
    } else {
        hipLaunchKernelGGL(pass1, dim3(NHEAD, 1), dim3(256), 0, stream,
                           K, V, slots, Sn);
    }
    hipLaunchKernelGGL(pass2, dim3(Sn / 64, NHEAD), dim3(256), 0, stream,
                       Q, slots, out);
}